// Round 12
// baseline (260.331 us; speedup 1.0000x reference)
//
#include <hip/hip_runtime.h>
#include <math.h>

#define IMG 1024
#define NXT 26              // x tiles: 40 output cols each (26*40=1040 >= 1024)
#define NYT 16              // y tiles: 64 output rows each

// R12 = R11 (register-resident fused in-place wave tile, 128-VGPR cap) +
//  (1) bound_ctrl=1 DPP shifts: shifted-in lanes get 0 instead of preserved
//      old -> no v_mov preload per shift (~12% VALU). A 0 entering the erode
//      min / targ AND corrupts only lanes 0/63, spreading <=1 lane/step ->
//      after 11 erodes + dilate wrong lanes are {0..11,52..63} = discarded
//      halo; outputs (lanes 12..51) unaffected. Dilate shifts wanted 0 anyway.
//  (2) single-launch finalize: partials + device atomic counter in ws; last
//      block re-reduces in fixed order (deterministic) and writes out[0].
//      Counter zeroed by a 64B hipMemsetAsync (graph-capturable).
typedef _Float16 h2 __attribute__((ext_vector_type(2)));
union UH { unsigned u; h2 h; };
__device__ __forceinline__ h2 u2h(unsigned u){ UH x; x.u=u; return x.h; }
__device__ __forceinline__ unsigned h2u(h2 h){ UH x; x.h=h; return x.u; }
__device__ __forceinline__ h2 pmin(h2 a,h2 b){ return __builtin_elementwise_min(a,b); }
__device__ __forceinline__ h2 pmax(h2 a,h2 b){ return __builtin_elementwise_max(a,b); }
// {.x = lo_src.y, .y = hi_src.x} : row-pair shift helper (v_alignbit)
__device__ __forceinline__ h2 funnel(h2 hi_src,h2 lo_src){ return u2h((h2u(lo_src)>>16)|(h2u(hi_src)<<16)); }
// full-wave lane shifts, bound_ctrl=1: shifted-in lane reads 0 (single
// v_mov_b32_dpp, no dst preload). wave_shr=0x138, wave_shl=0x130.
__device__ __forceinline__ unsigned wshr0(unsigned src){
  return (unsigned)__builtin_amdgcn_update_dpp(0, (int)src, 0x138, 0xF, 0xF, true);
}
__device__ __forceinline__ unsigned wshl0(unsigned src){
  return (unsigned)__builtin_amdgcn_update_dpp(0, (int)src, 0x130, 0xF, 0xF, true);
}
__device__ __forceinline__ float sigmoidf(float x){ return 1.0f/(1.0f+__expf(-x)); }

template<bool BND>
__device__ __forceinline__ void wave_tile(const float* __restrict__ pb, const int* __restrict__ tb,
                                          int or0, int oc0, int lane, float (&s)[7]){
  const int c  = oc0 - 12 + lane;
  const bool cv = (unsigned)c < (unsigned)IMG;
  const int cc = BND ? (c<0?0:(c>IMG-1?IMG-1:c)) : c;
  int lo=0, hi=88;
  unsigned pm0=~0u, pm1=~0u, pm2=0x00FFFFFFu;   // dilate-valid masks (bits in-image)
  if (BND){
    lo = (or0<0)? -or0 : 0;                      // valid local rows [lo,hi), both even
    hi = (IMG-or0<88)? IMG-or0 : 88;
    unsigned m[3];
    #pragma unroll
    for (int w=0;w<3;++w){
      int l = lo-32*w; l=l<0?0:(l>32?32:l);
      int h = hi-32*w; h=h<0?0:(h>32?32:h);
      unsigned mm=0;
      if (h>l){ unsigned top=(h>=32)?~0u:((1u<<h)-1u); unsigned bot=(l<=0)?0u:((1u<<l)-1u); mm=top&~bot; }
      m[w]=mm;
    }
    unsigned cin = cv?0u:~0u;
    pm0=m[0]&~cin; pm1=m[1]&~cin; pm2=m[2]&~cin;
  }
  const h2 twos  = {(_Float16)2.0f,(_Float16)2.0f};
  const h2 zerov = {(_Float16)0.0f,(_Float16)0.0f};

  h2 S[44], skel[32];
  unsigned t0=0,t1=0,t2=0xFF000000u;             // pseudo rows 88..95 erode-neutral 1
  // ---- stage (88 rows; one row per load instr = 256B coalesced across lanes) ----
  #pragma unroll
  for (int k=0;k<44;++k){
    int r0=or0+2*k, r1=r0+1;
    int g0 = BND ? (r0<0?0:(r0>IMG-1?IMG-1:r0)) : r0;
    int g1 = BND ? (r1<0?0:(r1>IMG-1?IMG-1:r1)) : r1;
    float x0 = pb[(long)g0*IMG+cc];
    float x1 = pb[(long)g1*IMG+cc];
    int v0 = tb[(long)g0*IMG+cc];
    int v1 = tb[(long)g1*IMG+cc];
    h2 hh; hh.x=(_Float16)sigmoidf(x0); hh.y=(_Float16)sigmoidf(x1);
    if (BND){
      bool bad = (2*k < lo) || (2*k >= hi);      // pair-uniform (lo,hi even)
      hh = (bad || !cv) ? twos : hh;             // one-time +inf seed
    }
    S[k]=hh;
    unsigned add = ((unsigned)(v0!=0)<<((2*k)&31)) | ((unsigned)(v1!=0)<<((2*k+1)&31));
    if (k<16) t0|=add; else if (k<32) t1|=add; else t2|=add;
  }
  if (BND){ t0 |= ~pm0; t1 |= ~pm1; t2 |= ~pm2; }  // one-time erode-neutral 1 seed
  const unsigned q0=t0,q1=t1,q2=t2;
  unsigned sk0=0,sk1=0,sk2=0;
  #pragma unroll
  for (int i=0;i<32;++i) skel[i]=zerov;

  #pragma unroll 1
  for (int j=0;j<11;++j){
    // ---- targ erode + dilate + skel_t bits ----
    {
      unsigned o0=t0,o1=t1,o2=t2;
      unsigned U0=(t0<<1)|1u,       U1=(t1<<1)|(t0>>31), U2=(t2<<1)|(t1>>31);
      unsigned D0=(t0>>1)|(t1<<31), D1=(t1>>1)|(t2<<31), D2=(t2>>1)|0x80000000u;
      unsigned L0=wshr0(t0), L1=wshr0(t1), L2=wshr0(t2);   // lane-edge 0: halo-safe
      unsigned R0=wshl0(t0), R1=wshl0(t1), R2=wshl0(t2);
      t0 &= U0&D0&L0&R0; t1 &= U1&D1&L1&R1; t2 &= U2&D2&L2&R2;
      unsigned g0=t0, g1=t1, g2=t2;
      if (BND){ g0&=pm0; g1&=pm1; g2&=pm2; }     // dilate needs masked-to-0 inputs
      unsigned V0 = g0|(g0<<1)|((g0>>1)|(g1<<31));
      unsigned V1 = g1|((g1<<1)|(g0>>31))|((g1>>1)|(g2<<31));
      unsigned V2 = g2|((g2<<1)|(g1>>31))|(g2>>1);
      unsigned d0 = V0|wshr0(V0)|wshl0(V0);
      unsigned d1 = V1|wshr0(V1)|wshl0(V1);
      unsigned d2 = V2|wshr0(V2)|wshl0(V2);
      sk0 |= o0&~d0; sk1 |= o1&~d1; sk2 |= o2&~d2;
    }
    // ---- fused in-place pred erode (5-cross min) + 3x3 dilate + skel ----
    {
      h2 pf = funnel(S[0], twos);                // su for k=0 (rows -1,0)
      h2 est1 = zerov;                           // raw e[k-1] (store-back)
      h2 dm1  = zerov;                           // masked e[k-1] (dilate input)
      h2 fprev= zerov;                           // fU(k-1) = funnel(e[k-1]m, e[k-2]m)
      #pragma unroll
      for (int k=0;k<44;++k){
        h2 mc = S[k];
        h2 mn = (k<43)? S[k+1] : twos;
        h2 sd = funnel(mn, mc);
        h2 v3 = pmin(pmin(pf,sd), mc);
        pf = sd;
        h2 l3 = u2h(wshr0(h2u(mc)));             // lane 0 gets 0.0: wrong only in
        h2 r3 = u2h(wshl0(h2u(mc)));             // decaying lane-halo (see header)
        h2 ek = pmin(pmin(l3,r3), v3);           // e[k] = erode pair k
        h2 ekm = ek;
        if (BND){
          bool bad = (2*k < lo) || (2*k >= hi);
          ekm = (bad || !cv) ? zerov : ek;       // max-filter: OOB -> 0 each step
        }
        h2 fcur = zerov;
        if (k>=6) fcur = funnel(ekm, dm1);       // fU(k) = fD(k-1)
        if (k>=7 && k<=38){
          const int p = k-1;                     // output pairs 6..37
          h2 vm = pmax(pmax(fprev,fcur), dm1);   // vertical max3 of e at pair p
          h2 lm = u2h(wshr0(h2u(vm)));
          h2 rr = u2h(wshl0(h2u(vm)));
          h2 hm = pmax(pmax(lm,rr), vm);         // 3x3 dilate
          h2 d  = pmax(S[p]-hm, zerov);          // original S[p] (not yet stored)
          h2 x2 = d - skel[p-6]*d;
          skel[p-6] = skel[p-6] + pmax(x2, zerov);
        }
        if (k>=1) S[k-1] = est1;                 // store e[k-1] (all readers done)
        est1 = ek; dm1 = ekm; fprev = fcur;
      }
      S[43] = est1;
    }
  }

  // ---- sums; pred reloaded (output rows always in-image) ----
  #pragma unroll
  for (int k2=0;k2<7;++k2) s[k2]=0.f;
  #pragma unroll
  for (int i=0;i<32;++i){
    int k=i+6;
    long r0 = (long)(or0+2*k);
    float x0 = pb[r0*IMG+cc], x1 = pb[(r0+1)*IMG+cc];
    float p0 = sigmoidf(x0), p1 = sigmoidf(x1);
    int b=(2*k)&31, w=(2*k)>>5;
    unsigned qw = (w==0)?q0:((w==1)?q1:q2);
    unsigned sw = (w==0)?sk0:((w==1)?sk1:sk2);
    float a0=(float)skel[i].x, a1=(float)skel[i].y;
    float tb0=(float)((qw>>b)&1u), tb1=(float)((qw>>(b+1))&1u);
    float sb0=(float)((sw>>b)&1u), sb1=(float)((sw>>(b+1))&1u);
    s[0]+=a0+a1;          s[1]+=a0*tb0+a1*tb1;
    s[2]+=sb0+sb1;        s[3]+=sb0*p0+sb1*p1;
    s[4]+=p0*tb0+p1*tb1;  s[5]+=p0+p1;  s[6]+=tb0+tb1;
  }
}

// ws layout: [0..1] uint counter (64B memset covers); partials at float idx 8+blk*8
__global__ __launch_bounds__(128,2)
void cl_dice_main(const float* __restrict__ pred, const int* __restrict__ targ,
                  float* __restrict__ ws, float* __restrict__ out, int nblk){
  __shared__ float red[2][8];
  __shared__ unsigned lastFlag;
  const int tid=threadIdx.x, lane=tid&63, wv=tid>>6;
  const int wid = blockIdx.x*2 + wv;
  const int tx = wid % NXT; const int tt = wid/NXT;
  const int ty = tt % NYT;  const int z  = tt/NYT;
  const long base = (long)z*IMG*IMG;
  const int or0 = ty*64-12, oc0 = tx*40;
  const bool bnd = (tx==0)|(tx==NXT-1)|(ty==0)|(ty==NYT-1);
  float s[7];
  if (!bnd) wave_tile<false>(pred+base, targ+base, or0, oc0, lane, s);
  else      wave_tile<true >(pred+base, targ+base, or0, oc0, lane, s);
  const int c = oc0-12+lane;
  const float msk = ((lane>=12)&&(lane<=51)&&(c<IMG)) ? 1.f : 0.f;
  #pragma unroll
  for (int k=0;k<7;++k){
    float v = s[k]*msk;
    v+=__shfl_down(v,32); v+=__shfl_down(v,16); v+=__shfl_down(v,8);
    v+=__shfl_down(v,4);  v+=__shfl_down(v,2);  v+=__shfl_down(v,1);
    if (lane==0) red[wv][k]=v;
  }
  __syncthreads();
  if (tid<7) ws[8 + blockIdx.x*8 + tid] = red[0][tid]+red[1][tid];
  __threadfence();                               // partials device-visible
  __syncthreads();
  if (tid==0){
    unsigned old = atomicAdd((unsigned*)ws, 1u); // device-scope counter
    lastFlag = (old == (unsigned)(nblk-1)) ? 1u : 0u;
  }
  __syncthreads();
  if (lastFlag){
    __threadfence();                             // acquire side
    float acc[7]={0,0,0,0,0,0,0};
    for (int i=tid; i<nblk; i+=128){
      const float* p = ws + 8 + i*8;
      #pragma unroll
      for (int k=0;k<7;++k) acc[k] += p[k];
    }
    #pragma unroll
    for (int k=0;k<7;++k){
      float v = acc[k];
      v+=__shfl_down(v,32); v+=__shfl_down(v,16); v+=__shfl_down(v,8);
      v+=__shfl_down(v,4);  v+=__shfl_down(v,2);  v+=__shfl_down(v,1);
      if (lane==0) red[wv][k]=v;
    }
    __syncthreads();
    if (tid==0){
      float t0v[7];
      #pragma unroll
      for (int k=0;k<7;++k) t0v[k] = red[0][k]+red[1][k];
      float sum_sp = t0v[0], sum_spt = t0v[1], sum_st = t0v[2], sum_stp = t0v[3];
      float inter  = t0v[4], sum_p   = t0v[5], sum_t  = t0v[6];
      float tprec = (sum_spt + 1.0f) / (sum_sp + 1.0f);
      float tsens = (sum_stp + 1.0f) / (sum_st + 1.0f);
      float cl    = 2.0f * tprec * tsens / (tprec + tsens + 1e-7f);
      float dice  = (2.0f * inter + 1.0f) / (sum_p + sum_t + 1.0f);
      out[0] = 1.0f - 0.5f * (dice + cl);
    }
  }
}

extern "C" void kernel_launch(void* const* d_in, const int* in_sizes, int n_in,
                              void* d_out, int out_size, void* d_ws, size_t ws_size,
                              hipStream_t stream) {
  const float* pred = (const float*)d_in[0];
  const int*   targ = (const int*)d_in[1];
  float* ws  = (float*)d_ws;
  float* out = (float*)d_out;

  const int B = in_sizes[0] / (IMG * IMG);     // 8
  const int nw   = NXT*NYT*B;                  // 3328 waves
  const int nblk = nw / 2;                     // 1664 blocks x 128 threads
  hipMemsetAsync(d_ws, 0, 64, stream);         // zero the done-counter
  cl_dice_main<<<nblk, 128, 0, stream>>>(pred, targ, ws, out, nblk);
}

// Round 13
// 216.937 us; speedup vs baseline: 1.2000x; 1.2000x over previous
//
#include <hip/hip_runtime.h>
#include <math.h>

#define IMG 1024
#define NXT 26              // x tiles: 40 output cols each (26*40=1040 >= 1024)
#define NYT 16              // y tiles: 64 output rows each

// R13 = R12's wave_tile (bound_ctrl=1 DPP shifts: -9% VALU cycles, measured)
//     + R11's two-kernel finalize (the R12 fused finalize cost +35us of stall:
//       __threadfence = device-scope release = cross-XCD L2 writeback per
//       block x 1664 blocks; revert).
// Register-resident fused in-place wave tile, 128-VGPR cap (launch_bounds
// arg2 mapping measured: cap = 256/arg2; arg2=2 -> 128 -> 4 waves/SIMD).
typedef _Float16 h2 __attribute__((ext_vector_type(2)));
union UH { unsigned u; h2 h; };
__device__ __forceinline__ h2 u2h(unsigned u){ UH x; x.u=u; return x.h; }
__device__ __forceinline__ unsigned h2u(h2 h){ UH x; x.h=h; return x.u; }
__device__ __forceinline__ h2 pmin(h2 a,h2 b){ return __builtin_elementwise_min(a,b); }
__device__ __forceinline__ h2 pmax(h2 a,h2 b){ return __builtin_elementwise_max(a,b); }
// {.x = lo_src.y, .y = hi_src.x} : row-pair shift helper (v_alignbit)
__device__ __forceinline__ h2 funnel(h2 hi_src,h2 lo_src){ return u2h((h2u(lo_src)>>16)|(h2u(hi_src)<<16)); }
// full-wave lane shifts, bound_ctrl=1: shifted-in lane reads 0 (single
// v_mov_b32_dpp, no dst preload). wave_shr=0x138, wave_shl=0x130.
// The injected 0 corrupts only lanes 0/63, spreading <=1 lane/step -> after
// 11 erodes + dilate the wrong lanes are {0..11,52..63} = discarded halo.
__device__ __forceinline__ unsigned wshr0(unsigned src){
  return (unsigned)__builtin_amdgcn_update_dpp(0, (int)src, 0x138, 0xF, 0xF, true);
}
__device__ __forceinline__ unsigned wshl0(unsigned src){
  return (unsigned)__builtin_amdgcn_update_dpp(0, (int)src, 0x130, 0xF, 0xF, true);
}
__device__ __forceinline__ float sigmoidf(float x){ return 1.0f/(1.0f+__expf(-x)); }

template<bool BND>
__device__ __forceinline__ void wave_tile(const float* __restrict__ pb, const int* __restrict__ tb,
                                          int or0, int oc0, int lane, float (&s)[7]){
  const int c  = oc0 - 12 + lane;
  const bool cv = (unsigned)c < (unsigned)IMG;
  const int cc = BND ? (c<0?0:(c>IMG-1?IMG-1:c)) : c;
  int lo=0, hi=88;
  unsigned pm0=~0u, pm1=~0u, pm2=0x00FFFFFFu;   // dilate-valid masks (bits in-image)
  if (BND){
    lo = (or0<0)? -or0 : 0;                      // valid local rows [lo,hi), both even
    hi = (IMG-or0<88)? IMG-or0 : 88;
    unsigned m[3];
    #pragma unroll
    for (int w=0;w<3;++w){
      int l = lo-32*w; l=l<0?0:(l>32?32:l);
      int h = hi-32*w; h=h<0?0:(h>32?32:h);
      unsigned mm=0;
      if (h>l){ unsigned top=(h>=32)?~0u:((1u<<h)-1u); unsigned bot=(l<=0)?0u:((1u<<l)-1u); mm=top&~bot; }
      m[w]=mm;
    }
    unsigned cin = cv?0u:~0u;
    pm0=m[0]&~cin; pm1=m[1]&~cin; pm2=m[2]&~cin;
  }
  const h2 twos  = {(_Float16)2.0f,(_Float16)2.0f};
  const h2 zerov = {(_Float16)0.0f,(_Float16)0.0f};

  h2 S[44], skel[32];
  unsigned t0=0,t1=0,t2=0xFF000000u;             // pseudo rows 88..95 erode-neutral 1
  // ---- stage (88 rows; one row per load instr = 256B coalesced across lanes) ----
  #pragma unroll
  for (int k=0;k<44;++k){
    int r0=or0+2*k, r1=r0+1;
    int g0 = BND ? (r0<0?0:(r0>IMG-1?IMG-1:r0)) : r0;
    int g1 = BND ? (r1<0?0:(r1>IMG-1?IMG-1:r1)) : r1;
    float x0 = pb[(long)g0*IMG+cc];
    float x1 = pb[(long)g1*IMG+cc];
    int v0 = tb[(long)g0*IMG+cc];
    int v1 = tb[(long)g1*IMG+cc];
    h2 hh; hh.x=(_Float16)sigmoidf(x0); hh.y=(_Float16)sigmoidf(x1);
    if (BND){
      bool bad = (2*k < lo) || (2*k >= hi);      // pair-uniform (lo,hi even)
      hh = (bad || !cv) ? twos : hh;             // one-time +inf seed
    }
    S[k]=hh;
    unsigned add = ((unsigned)(v0!=0)<<((2*k)&31)) | ((unsigned)(v1!=0)<<((2*k+1)&31));
    if (k<16) t0|=add; else if (k<32) t1|=add; else t2|=add;
  }
  if (BND){ t0 |= ~pm0; t1 |= ~pm1; t2 |= ~pm2; }  // one-time erode-neutral 1 seed
  const unsigned q0=t0,q1=t1,q2=t2;
  unsigned sk0=0,sk1=0,sk2=0;
  #pragma unroll
  for (int i=0;i<32;++i) skel[i]=zerov;

  #pragma unroll 1
  for (int j=0;j<11;++j){
    // ---- targ erode + dilate + skel_t bits ----
    {
      unsigned o0=t0,o1=t1,o2=t2;
      unsigned U0=(t0<<1)|1u,       U1=(t1<<1)|(t0>>31), U2=(t2<<1)|(t1>>31);
      unsigned D0=(t0>>1)|(t1<<31), D1=(t1>>1)|(t2<<31), D2=(t2>>1)|0x80000000u;
      unsigned L0=wshr0(t0), L1=wshr0(t1), L2=wshr0(t2);   // lane-edge 0: halo-safe
      unsigned R0=wshl0(t0), R1=wshl0(t1), R2=wshl0(t2);
      t0 &= U0&D0&L0&R0; t1 &= U1&D1&L1&R1; t2 &= U2&D2&L2&R2;
      unsigned g0=t0, g1=t1, g2=t2;
      if (BND){ g0&=pm0; g1&=pm1; g2&=pm2; }     // dilate needs masked-to-0 inputs
      unsigned V0 = g0|(g0<<1)|((g0>>1)|(g1<<31));
      unsigned V1 = g1|((g1<<1)|(g0>>31))|((g1>>1)|(g2<<31));
      unsigned V2 = g2|((g2<<1)|(g1>>31))|(g2>>1);
      unsigned d0 = V0|wshr0(V0)|wshl0(V0);
      unsigned d1 = V1|wshr0(V1)|wshl0(V1);
      unsigned d2 = V2|wshr0(V2)|wshl0(V2);
      sk0 |= o0&~d0; sk1 |= o1&~d1; sk2 |= o2&~d2;
    }
    // ---- fused in-place pred erode (5-cross min) + 3x3 dilate + skel ----
    {
      h2 pf = funnel(S[0], twos);                // su for k=0 (rows -1,0)
      h2 est1 = zerov;                           // raw e[k-1] (store-back)
      h2 dm1  = zerov;                           // masked e[k-1] (dilate input)
      h2 fprev= zerov;                           // fU(k-1) = funnel(e[k-1]m, e[k-2]m)
      #pragma unroll
      for (int k=0;k<44;++k){
        h2 mc = S[k];
        h2 mn = (k<43)? S[k+1] : twos;
        h2 sd = funnel(mn, mc);
        h2 v3 = pmin(pmin(pf,sd), mc);
        pf = sd;
        h2 l3 = u2h(wshr0(h2u(mc)));             // lane 0 gets 0.0: wrong only in
        h2 r3 = u2h(wshl0(h2u(mc)));             // decaying lane-halo (see header)
        h2 ek = pmin(pmin(l3,r3), v3);           // e[k] = erode pair k
        h2 ekm = ek;
        if (BND){
          bool bad = (2*k < lo) || (2*k >= hi);
          ekm = (bad || !cv) ? zerov : ek;       // max-filter: OOB -> 0 each step
        }
        h2 fcur = zerov;
        if (k>=6) fcur = funnel(ekm, dm1);       // fU(k) = fD(k-1)
        if (k>=7 && k<=38){
          const int p = k-1;                     // output pairs 6..37
          h2 vm = pmax(pmax(fprev,fcur), dm1);   // vertical max3 of e at pair p
          h2 lm = u2h(wshr0(h2u(vm)));
          h2 rr = u2h(wshl0(h2u(vm)));
          h2 hm = pmax(pmax(lm,rr), vm);         // 3x3 dilate
          h2 d  = pmax(S[p]-hm, zerov);          // original S[p] (not yet stored)
          h2 x2 = d - skel[p-6]*d;
          skel[p-6] = skel[p-6] + pmax(x2, zerov);
        }
        if (k>=1) S[k-1] = est1;                 // store e[k-1] (all readers done)
        est1 = ek; dm1 = ekm; fprev = fcur;
      }
      S[43] = est1;
    }
  }

  // ---- sums; pred reloaded (output rows always in-image) ----
  #pragma unroll
  for (int k2=0;k2<7;++k2) s[k2]=0.f;
  #pragma unroll
  for (int i=0;i<32;++i){
    int k=i+6;
    long r0 = (long)(or0+2*k);
    float x0 = pb[r0*IMG+cc], x1 = pb[(r0+1)*IMG+cc];
    float p0 = sigmoidf(x0), p1 = sigmoidf(x1);
    int b=(2*k)&31, w=(2*k)>>5;
    unsigned qw = (w==0)?q0:((w==1)?q1:q2);
    unsigned sw = (w==0)?sk0:((w==1)?sk1:sk2);
    float a0=(float)skel[i].x, a1=(float)skel[i].y;
    float tb0=(float)((qw>>b)&1u), tb1=(float)((qw>>(b+1))&1u);
    float sb0=(float)((sw>>b)&1u), sb1=(float)((sw>>(b+1))&1u);
    s[0]+=a0+a1;          s[1]+=a0*tb0+a1*tb1;
    s[2]+=sb0+sb1;        s[3]+=sb0*p0+sb1*p1;
    s[4]+=p0*tb0+p1*tb1;  s[5]+=p0+p1;  s[6]+=tb0+tb1;
  }
}

__global__ __launch_bounds__(128,2)
void cl_dice_main(const float* __restrict__ pred, const int* __restrict__ targ,
                  float* __restrict__ ws){
  __shared__ float red[2][8];
  const int tid=threadIdx.x, lane=tid&63, wv=tid>>6;
  const int wid = blockIdx.x*2 + wv;
  const int tx = wid % NXT; const int tt = wid/NXT;
  const int ty = tt % NYT;  const int z  = tt/NYT;
  const long base = (long)z*IMG*IMG;
  const int or0 = ty*64-12, oc0 = tx*40;
  const bool bnd = (tx==0)|(tx==NXT-1)|(ty==0)|(ty==NYT-1);
  float s[7];
  if (!bnd) wave_tile<false>(pred+base, targ+base, or0, oc0, lane, s);
  else      wave_tile<true >(pred+base, targ+base, or0, oc0, lane, s);
  const int c = oc0-12+lane;
  const float msk = ((lane>=12)&&(lane<=51)&&(c<IMG)) ? 1.f : 0.f;
  #pragma unroll
  for (int k=0;k<7;++k){
    float v = s[k]*msk;
    v+=__shfl_down(v,32); v+=__shfl_down(v,16); v+=__shfl_down(v,8);
    v+=__shfl_down(v,4);  v+=__shfl_down(v,2);  v+=__shfl_down(v,1);
    if (lane==0) red[wv][k]=v;
  }
  __syncthreads();
  if (tid<7) ws[blockIdx.x*8+tid] = red[0][tid]+red[1][tid];
}

__global__ __launch_bounds__(256)
void cl_dice_finalize(const float* __restrict__ ws, float* __restrict__ out, int nblk) {
  __shared__ float red[4][8];
  int tid = threadIdx.x;
  float acc[7] = {0,0,0,0,0,0,0};
  for (int i=tid; i<nblk; i+=256) {
    #pragma unroll
    for (int k=0;k<7;++k) acc[k] += ws[i*8 + k];
  }
  #pragma unroll
  for (int k=0;k<7;++k){
    float v = acc[k];
    v += __shfl_down(v,32); v += __shfl_down(v,16); v += __shfl_down(v,8);
    v += __shfl_down(v,4);  v += __shfl_down(v,2);  v += __shfl_down(v,1);
    if ((tid & 63) == 0) red[tid>>6][k] = v;
  }
  __syncthreads();
  if (tid == 0) {
    float t0[7];
    #pragma unroll
    for (int k=0;k<7;++k) t0[k] = red[0][k] + red[1][k] + red[2][k] + red[3][k];
    float sum_sp = t0[0], sum_spt = t0[1], sum_st = t0[2], sum_stp = t0[3];
    float inter  = t0[4], sum_p   = t0[5], sum_t  = t0[6];
    float tprec = (sum_spt + 1.0f) / (sum_sp + 1.0f);
    float tsens = (sum_stp + 1.0f) / (sum_st + 1.0f);
    float cl    = 2.0f * tprec * tsens / (tprec + tsens + 1e-7f);
    float dice  = (2.0f * inter + 1.0f) / (sum_p + sum_t + 1.0f);
    out[0] = 1.0f - 0.5f * (dice + cl);
  }
}

extern "C" void kernel_launch(void* const* d_in, const int* in_sizes, int n_in,
                              void* d_out, int out_size, void* d_ws, size_t ws_size,
                              hipStream_t stream) {
  const float* pred = (const float*)d_in[0];
  const int*   targ = (const int*)d_in[1];
  float* ws  = (float*)d_ws;
  float* out = (float*)d_out;

  const int B = in_sizes[0] / (IMG * IMG);     // 8
  const int nw   = NXT*NYT*B;                  // 3328 waves
  const int nblk = nw / 2;                     // 1664 blocks x 128 threads
  cl_dice_main<<<nblk, 128, 0, stream>>>(pred, targ, ws);
  cl_dice_finalize<<<1, 256, 0, stream>>>(ws, out, nblk);
}

// Round 15
// 214.669 us; speedup vs baseline: 1.2127x; 1.0106x over previous
//
#include <hip/hip_runtime.h>
#include <math.h>

#define IMG 1024
#define NXT 26              // x tiles: 40 output cols each (26*40=1040 >= 1024)
#define NYT 16              // y tiles: 64 output rows each

// R14 = R13 (register-resident fused in-place wave tile, bound_ctrl DPP,
// two-kernel finalize) + final VALU trims:
//  (1) skel += d - skel*d (drop redundant relu: d>=0, skel in [0,1] by
//      induction in the valid region; halo skel is garbage but pointwise
//      state never mixes spatially and sums read only valid rows/lanes).
//  (2) s[2]/s[6] (pure bit counts over output rows 12..75) via __popc
//      instead of per-bit extract+cvt+add.
typedef _Float16 h2 __attribute__((ext_vector_type(2)));
union UH { unsigned u; h2 h; };
__device__ __forceinline__ h2 u2h(unsigned u){ UH x; x.u=u; return x.h; }
__device__ __forceinline__ unsigned h2u(h2 h){ UH x; x.h=h; return x.u; }
__device__ __forceinline__ h2 pmin(h2 a,h2 b){ return __builtin_elementwise_min(a,b); }
__device__ __forceinline__ h2 pmax(h2 a,h2 b){ return __builtin_elementwise_max(a,b); }
// {.x = lo_src.y, .y = hi_src.x} : row-pair shift helper (v_alignbit)
__device__ __forceinline__ h2 funnel(h2 hi_src,h2 lo_src){ return u2h((h2u(lo_src)>>16)|(h2u(hi_src)<<16)); }
// full-wave lane shifts, bound_ctrl=1: shifted-in lane reads 0 (single
// v_mov_b32_dpp, no dst preload). wave_shr=0x138, wave_shl=0x130.
// The injected 0 corrupts only lanes 0/63, spreading <=1 lane/step -> after
// 11 erodes + dilate the wrong lanes are {0..11,52..63} = discarded halo.
__device__ __forceinline__ unsigned wshr0(unsigned src){
  return (unsigned)__builtin_amdgcn_update_dpp(0, (int)src, 0x138, 0xF, 0xF, true);
}
__device__ __forceinline__ unsigned wshl0(unsigned src){
  return (unsigned)__builtin_amdgcn_update_dpp(0, (int)src, 0x130, 0xF, 0xF, true);
}
__device__ __forceinline__ float sigmoidf(float x){ return 1.0f/(1.0f+__expf(-x)); }

template<bool BND>
__device__ __forceinline__ void wave_tile(const float* __restrict__ pb, const int* __restrict__ tb,
                                          int or0, int oc0, int lane, float (&s)[7]){
  const int c  = oc0 - 12 + lane;
  const bool cv = (unsigned)c < (unsigned)IMG;
  const int cc = BND ? (c<0?0:(c>IMG-1?IMG-1:c)) : c;
  int lo=0, hi=88;
  unsigned pm0=~0u, pm1=~0u, pm2=0x00FFFFFFu;   // dilate-valid masks (bits in-image)
  if (BND){
    lo = (or0<0)? -or0 : 0;                      // valid local rows [lo,hi), both even
    hi = (IMG-or0<88)? IMG-or0 : 88;
    unsigned m[3];
    #pragma unroll
    for (int w=0;w<3;++w){
      int l = lo-32*w; l=l<0?0:(l>32?32:l);
      int h = hi-32*w; h=h<0?0:(h>32?32:h);
      unsigned mm=0;
      if (h>l){ unsigned top=(h>=32)?~0u:((1u<<h)-1u); unsigned bot=(l<=0)?0u:((1u<<l)-1u); mm=top&~bot; }
      m[w]=mm;
    }
    unsigned cin = cv?0u:~0u;
    pm0=m[0]&~cin; pm1=m[1]&~cin; pm2=m[2]&~cin;
  }
  const h2 twos  = {(_Float16)2.0f,(_Float16)2.0f};
  const h2 zerov = {(_Float16)0.0f,(_Float16)0.0f};

  h2 S[44], skel[32];
  unsigned t0=0,t1=0,t2=0xFF000000u;             // pseudo rows 88..95 erode-neutral 1
  // ---- stage (88 rows; one row per load instr = 256B coalesced across lanes) ----
  #pragma unroll
  for (int k=0;k<44;++k){
    int r0=or0+2*k, r1=r0+1;
    int g0 = BND ? (r0<0?0:(r0>IMG-1?IMG-1:r0)) : r0;
    int g1 = BND ? (r1<0?0:(r1>IMG-1?IMG-1:r1)) : r1;
    float x0 = pb[(long)g0*IMG+cc];
    float x1 = pb[(long)g1*IMG+cc];
    int v0 = tb[(long)g0*IMG+cc];
    int v1 = tb[(long)g1*IMG+cc];
    h2 hh; hh.x=(_Float16)sigmoidf(x0); hh.y=(_Float16)sigmoidf(x1);
    if (BND){
      bool bad = (2*k < lo) || (2*k >= hi);      // pair-uniform (lo,hi even)
      hh = (bad || !cv) ? twos : hh;             // one-time +inf seed
    }
    S[k]=hh;
    unsigned add = ((unsigned)(v0!=0)<<((2*k)&31)) | ((unsigned)(v1!=0)<<((2*k+1)&31));
    if (k<16) t0|=add; else if (k<32) t1|=add; else t2|=add;
  }
  if (BND){ t0 |= ~pm0; t1 |= ~pm1; t2 |= ~pm2; }  // one-time erode-neutral 1 seed
  const unsigned q0=t0,q1=t1,q2=t2;
  unsigned sk0=0,sk1=0,sk2=0;
  #pragma unroll
  for (int i=0;i<32;++i) skel[i]=zerov;

  #pragma unroll 1
  for (int j=0;j<11;++j){
    // ---- targ erode + dilate + skel_t bits ----
    {
      unsigned o0=t0,o1=t1,o2=t2;
      unsigned U0=(t0<<1)|1u,       U1=(t1<<1)|(t0>>31), U2=(t2<<1)|(t1>>31);
      unsigned D0=(t0>>1)|(t1<<31), D1=(t1>>1)|(t2<<31), D2=(t2>>1)|0x80000000u;
      unsigned L0=wshr0(t0), L1=wshr0(t1), L2=wshr0(t2);   // lane-edge 0: halo-safe
      unsigned R0=wshl0(t0), R1=wshl0(t1), R2=wshl0(t2);
      t0 &= U0&D0&L0&R0; t1 &= U1&D1&L1&R1; t2 &= U2&D2&L2&R2;
      unsigned g0=t0, g1=t1, g2=t2;
      if (BND){ g0&=pm0; g1&=pm1; g2&=pm2; }     // dilate needs masked-to-0 inputs
      unsigned V0 = g0|(g0<<1)|((g0>>1)|(g1<<31));
      unsigned V1 = g1|((g1<<1)|(g0>>31))|((g1>>1)|(g2<<31));
      unsigned V2 = g2|((g2<<1)|(g1>>31))|(g2>>1);
      unsigned d0 = V0|wshr0(V0)|wshl0(V0);
      unsigned d1 = V1|wshr0(V1)|wshl0(V1);
      unsigned d2 = V2|wshr0(V2)|wshl0(V2);
      sk0 |= o0&~d0; sk1 |= o1&~d1; sk2 |= o2&~d2;
    }
    // ---- fused in-place pred erode (5-cross min) + 3x3 dilate + skel ----
    {
      h2 pf = funnel(S[0], twos);                // su for k=0 (rows -1,0)
      h2 est1 = zerov;                           // raw e[k-1] (store-back)
      h2 dm1  = zerov;                           // masked e[k-1] (dilate input)
      h2 fprev= zerov;                           // fU(k-1) = funnel(e[k-1]m, e[k-2]m)
      #pragma unroll
      for (int k=0;k<44;++k){
        h2 mc = S[k];
        h2 mn = (k<43)? S[k+1] : twos;
        h2 sd = funnel(mn, mc);
        h2 v3 = pmin(pmin(pf,sd), mc);
        pf = sd;
        h2 l3 = u2h(wshr0(h2u(mc)));             // lane 0 gets 0.0: wrong only in
        h2 r3 = u2h(wshl0(h2u(mc)));             // decaying lane-halo (see header)
        h2 ek = pmin(pmin(l3,r3), v3);           // e[k] = erode pair k
        h2 ekm = ek;
        if (BND){
          bool bad = (2*k < lo) || (2*k >= hi);
          ekm = (bad || !cv) ? zerov : ek;       // max-filter: OOB -> 0 each step
        }
        h2 fcur = zerov;
        if (k>=6) fcur = funnel(ekm, dm1);       // fU(k) = fD(k-1)
        if (k>=7 && k<=38){
          const int p = k-1;                     // output pairs 6..37
          h2 vm = pmax(pmax(fprev,fcur), dm1);   // vertical max3 of e at pair p
          h2 lm = u2h(wshr0(h2u(vm)));
          h2 rr = u2h(wshl0(h2u(vm)));
          h2 hm = pmax(pmax(lm,rr), vm);         // 3x3 dilate
          h2 d  = pmax(S[p]-hm, zerov);          // original S[p] (not yet stored)
          // skel += d - skel*d  (relu dropped: d>=0, skel<=1 in valid region;
          // halo skel garbage is never read by the sums)
          h2 x2 = d - skel[p-6]*d;
          skel[p-6] = skel[p-6] + x2;
        }
        if (k>=1) S[k-1] = est1;                 // store e[k-1] (all readers done)
        est1 = ek; dm1 = ekm; fprev = fcur;
      }
      S[43] = est1;
    }
  }

  // ---- sums; pred reloaded (output rows always in-image) ----
  #pragma unroll
  for (int k2=0;k2<7;++k2) s[k2]=0.f;
  // pure-bit sums over output rows 12..75 (bits 12..31 | 32..63 | 64..75)
  s[6] = (float)(__popc(q0 & 0xFFFFF000u) + __popc(q1) + __popc(q2 & 0x00000FFFu));
  s[2] = (float)(__popc(sk0 & 0xFFFFF000u) + __popc(sk1) + __popc(sk2 & 0x00000FFFu));
  #pragma unroll
  for (int i=0;i<32;++i){
    int k=i+6;
    long r0 = (long)(or0+2*k);
    float x0 = pb[r0*IMG+cc], x1 = pb[(r0+1)*IMG+cc];
    float p0 = sigmoidf(x0), p1 = sigmoidf(x1);
    int b=(2*k)&31, w=(2*k)>>5;
    unsigned qw = (w==0)?q0:((w==1)?q1:q2);
    unsigned sw = (w==0)?sk0:((w==1)?sk1:sk2);
    float a0=(float)skel[i].x, a1=(float)skel[i].y;
    float tb0=(float)((qw>>b)&1u), tb1=(float)((qw>>(b+1))&1u);
    float sb0=(float)((sw>>b)&1u), sb1=(float)((sw>>(b+1))&1u);
    s[0]+=a0+a1;          s[1]+=a0*tb0+a1*tb1;
    s[3]+=sb0*p0+sb1*p1;
    s[4]+=p0*tb0+p1*tb1;  s[5]+=p0+p1;
  }
}

__global__ __launch_bounds__(128,2)
void cl_dice_main(const float* __restrict__ pred, const int* __restrict__ targ,
                  float* __restrict__ ws){
  __shared__ float red[2][8];
  const int tid=threadIdx.x, lane=tid&63, wv=tid>>6;
  const int wid = blockIdx.x*2 + wv;
  const int tx = wid % NXT; const int tt = wid/NXT;
  const int ty = tt % NYT;  const int z  = tt/NYT;
  const long base = (long)z*IMG*IMG;
  const int or0 = ty*64-12, oc0 = tx*40;
  const bool bnd = (tx==0)|(tx==NXT-1)|(ty==0)|(ty==NYT-1);
  float s[7];
  if (!bnd) wave_tile<false>(pred+base, targ+base, or0, oc0, lane, s);
  else      wave_tile<true >(pred+base, targ+base, or0, oc0, lane, s);
  const int c = oc0-12+lane;
  const float msk = ((lane>=12)&&(lane<=51)&&(c<IMG)) ? 1.f : 0.f;
  #pragma unroll
  for (int k=0;k<7;++k){
    float v = s[k]*msk;
    v+=__shfl_down(v,32); v+=__shfl_down(v,16); v+=__shfl_down(v,8);
    v+=__shfl_down(v,4);  v+=__shfl_down(v,2);  v+=__shfl_down(v,1);
    if (lane==0) red[wv][k]=v;
  }
  __syncthreads();
  if (tid<7) ws[blockIdx.x*8+tid] = red[0][tid]+red[1][tid];
}

__global__ __launch_bounds__(256)
void cl_dice_finalize(const float* __restrict__ ws, float* __restrict__ out, int nblk) {
  __shared__ float red[4][8];
  int tid = threadIdx.x;
  float acc[7] = {0,0,0,0,0,0,0};
  for (int i=tid; i<nblk; i+=256) {
    #pragma unroll
    for (int k=0;k<7;++k) acc[k] += ws[i*8 + k];
  }
  #pragma unroll
  for (int k=0;k<7;++k){
    float v = acc[k];
    v += __shfl_down(v,32); v += __shfl_down(v,16); v += __shfl_down(v,8);
    v += __shfl_down(v,4);  v += __shfl_down(v,2);  v += __shfl_down(v,1);
    if ((tid & 63) == 0) red[tid>>6][k] = v;
  }
  __syncthreads();
  if (tid == 0) {
    float t0[7];
    #pragma unroll
    for (int k=0;k<7;++k) t0[k] = red[0][k] + red[1][k] + red[2][k] + red[3][k];
    float sum_sp = t0[0], sum_spt = t0[1], sum_st = t0[2], sum_stp = t0[3];
    float inter  = t0[4], sum_p   = t0[5], sum_t  = t0[6];
    float tprec = (sum_spt + 1.0f) / (sum_sp + 1.0f);
    float tsens = (sum_stp + 1.0f) / (sum_st + 1.0f);
    float cl    = 2.0f * tprec * tsens / (tprec + tsens + 1e-7f);
    float dice  = (2.0f * inter + 1.0f) / (sum_p + sum_t + 1.0f);
    out[0] = 1.0f - 0.5f * (dice + cl);
  }
}

extern "C" void kernel_launch(void* const* d_in, const int* in_sizes, int n_in,
                              void* d_out, int out_size, void* d_ws, size_t ws_size,
                              hipStream_t stream) {
  const float* pred = (const float*)d_in[0];
  const int*   targ = (const int*)d_in[1];
  float* ws  = (float*)d_ws;
  float* out = (float*)d_out;

  const int B = in_sizes[0] / (IMG * IMG);     // 8
  const int nw   = NXT*NYT*B;                  // 3328 waves
  const int nblk = nw / 2;                     // 1664 blocks x 128 threads
  cl_dice_main<<<nblk, 128, 0, stream>>>(pred, targ, ws);
  cl_dice_finalize<<<1, 256, 0, stream>>>(ws, out, nblk);
}